// Round 1
// baseline (416.096 us; speedup 1.0000x reference)
//
#include <hip/hip_runtime.h>
#include <hip/hip_bf16.h>

#define H_ 12
#define S_ 2048
#define D_ 64
#define QT 16
#define NEG_INF_F -1000000000.0f

typedef float f32x4 __attribute__((ext_vector_type(4)));
typedef int   i32x4 __attribute__((ext_vector_type(4)));
typedef short s16x8 __attribute__((ext_vector_type(8)));
typedef unsigned short u16x4 __attribute__((ext_vector_type(4)));

// round-to-nearest-even fp32 -> bf16 (values here are finite, no NaN concern)
static __device__ __forceinline__ unsigned short f2bf(float f) {
    unsigned int u = __builtin_bit_cast(unsigned int, f);
    u += 0x7FFFu + ((u >> 16) & 1u);
    return (unsigned short)(u >> 16);
}

// Fused: masked softmax (writes attn fp32) + PV via bf16 MFMA (writes out fp32).
// Block = 256 threads (4 waves), handles one head h and QT=16 q-rows.
__global__ __launch_bounds__(256, 2)
void ra_fused(const float* __restrict__ v,
              const float* __restrict__ scores,
              const int* __restrict__ mask,
              float* __restrict__ out_all)
{
    // P tile, bf16, [QT][S_], XOR-swizzled: byte ^= ((row&7)<<4)
    __shared__ __align__(16) unsigned short p_lds[QT * S_];   // 64 KB

    const int bid  = blockIdx.x;
    const int h    = bid % H_;           // consecutive blocks span heads -> mask L3 reuse
    const int qt   = bid / H_;
    const int qb   = qt * QT;
    const int tid  = threadIdx.x;
    const int wid  = tid >> 6;
    const int lane = tid & 63;

    float* outp = out_all;                                // [H][S][D]
    float* attn = out_all + (size_t)H_ * S_ * D_;         // [H][S][S]

    // ---------- Phase 1: masked softmax, wave per row, 4 rows per wave ----------
    for (int r = 0; r < 4; ++r) {
        const int row = wid * 4 + r;          // local row 0..15
        const int q   = qb + row;
        const float* srow = scores + ((size_t)h * S_ + q) * S_;
        const int*   mrow = mask + (size_t)q * S_;        // mask broadcast over h

        float sv[32];
        #pragma unroll
        for (int j = 0; j < 8; ++j) {
            const int k = j * 256 + lane * 4;
            f32x4 sc = *(const f32x4*)(srow + k);
            i32x4 mk = *(const i32x4*)(mrow + k);
            #pragma unroll
            for (int e = 0; e < 4; ++e)
                sv[j * 4 + e] = (mk[e] != 0) ? NEG_INF_F : sc[e];
        }

        float m = sv[0];
        #pragma unroll
        for (int i = 1; i < 32; ++i) m = fmaxf(m, sv[i]);
        #pragma unroll
        for (int off = 32; off > 0; off >>= 1) m = fmaxf(m, __shfl_xor(m, off, 64));

        float l = 0.f;
        #pragma unroll
        for (int i = 0; i < 32; ++i) { sv[i] = __expf(sv[i] - m); l += sv[i]; }
        #pragma unroll
        for (int off = 32; off > 0; off >>= 1) l += __shfl_xor(l, off, 64);
        const float inv = 1.0f / l;

        float* arow = attn + ((size_t)h * S_ + q) * S_;
        const int swz = (row & 7) << 4;
        #pragma unroll
        for (int j = 0; j < 8; ++j) {
            const int k = j * 256 + lane * 4;
            f32x4 av;
            u16x4 pv;
            #pragma unroll
            for (int e = 0; e < 4; ++e) {
                const float a = sv[j * 4 + e] * inv;
                av[e] = a;
                pv[e] = f2bf(a);
            }
            *(f32x4*)(arow + k) = av;                     // attn out, coalesced 16B
            const int boff = (row * (S_ * 2) + k * 2) ^ swz;
            *(u16x4*)((char*)p_lds + boff) = pv;          // bf16 P, swizzled ds_write_b64
        }
    }
    __syncthreads();

    // ---------- Phase 2: out = P @ v via mfma_f32_16x16x32_bf16 ----------
    // Wave wid owns output columns d0..d0+15. K-loop over 64 steps of 32.
    const int col  = lane & 15;
    const int kg   = lane >> 4;
    const int d0   = wid * 16;
    const int swzA = (col & 7) << 4;
    const float* vcol = v + (size_t)h * S_ * D_ + (d0 + col);

    f32x4 acc = {0.f, 0.f, 0.f, 0.f};
    #pragma unroll 2
    for (int ks = 0; ks < S_ / 32; ++ks) {
        const int ka = ks * 32 + kg * 8;      // lane's 8 contiguous k
        const int aoff = (col * (S_ * 2) + ka * 2) ^ swzA;
        s16x8 afrag = *(const s16x8*)((const char*)p_lds + aoff);  // ds_read_b128

        const float* vp = vcol + (size_t)ka * D_;
        s16x8 bfrag;
        #pragma unroll
        for (int i = 0; i < 8; ++i)
            bfrag[i] = (short)f2bf(vp[i * D_]);           // v is L2-resident

        acc = __builtin_amdgcn_mfma_f32_16x16x32_bf16(afrag, bfrag, acc, 0, 0, 0);
    }

    // C/D layout (m89-verified): col = lane&15, row = 4*(lane>>4) + j
    const int rg = (lane >> 4) * 4;
    #pragma unroll
    for (int j = 0; j < 4; ++j) {
        const int q = qb + rg + j;
        outp[((size_t)h * S_ + q) * D_ + d0 + col] = acc[j];
    }
}

extern "C" void kernel_launch(void* const* d_in, const int* in_sizes, int n_in,
                              void* d_out, int out_size, void* d_ws, size_t ws_size,
                              hipStream_t stream) {
    const float* v      = (const float*)d_in[0];  // (1,12,2048,64) f32
    const float* scores = (const float*)d_in[1];  // (1,12,2048,2048) f32
    const int*   mask   = (const int*)d_in[3];    // (1,1,2048,2048) i32
    float* out = (float*)d_out;                   // [out | attn] f32

    dim3 grid(H_ * (S_ / QT));
    dim3 block(256);
    hipLaunchKernelGGL(ra_fused, grid, block, 0, stream, v, scores, mask, out);
}

// Round 5
// 404.834 us; speedup vs baseline: 1.0278x; 1.0278x over previous
//
#include <hip/hip_runtime.h>
#include <hip/hip_bf16.h>

#define H_ 12
#define S_ 2048
#define D_ 64
#define QT 16
#define NEG_INF_F -1000000000.0f

typedef float f32x4 __attribute__((ext_vector_type(4)));
typedef int   i32x4 __attribute__((ext_vector_type(4)));
typedef short s16x8 __attribute__((ext_vector_type(8)));
typedef unsigned short u16x4 __attribute__((ext_vector_type(4)));

static __device__ __forceinline__ unsigned short f2bf(float f) {
    unsigned int u = __builtin_bit_cast(unsigned int, f);
    u += 0x7FFFu + ((u >> 16) & 1u);
    return (unsigned short)(u >> 16);
}

// Fused masked-softmax (writes attn fp32) + PV via bf16 MFMA (writes out fp32).
// Block = 512 threads (8 waves), one head h and QT=16 q-rows per block.
// LDS 64 KB -> 2 blocks/CU -> 16 waves/CU (launch_bounds caps VGPR at 128).
__global__ __launch_bounds__(512, 4)
void ra_fused(const float* __restrict__ v,
              const float* __restrict__ scores,
              const int* __restrict__ mask,
              float* __restrict__ out_all)
{
    // P tile, bf16, [QT][S_], XOR-swizzled: byte ^= ((row&7)<<4). 64 KB.
    // Reused after phase 2's MFMA loop as float[2][QT][D_] partial-sum scratch.
    __shared__ __align__(16) unsigned short p_lds[QT * S_];

    const int bid  = blockIdx.x;
    const int h    = bid % H_;           // consecutive blocks share mask rows -> L3 reuse
    const int qt   = bid / H_;
    const int qb   = qt * QT;
    const int tid  = threadIdx.x;
    const int wid  = tid >> 6;           // 0..7
    const int lane = tid & 63;

    float* outp = out_all;                                // [H][S][D]
    float* attn = out_all + (size_t)H_ * S_ * D_;         // [H][S][S]

    // ---------- Phase 1: masked softmax, wave per row, 2 rows per wave ----------
    for (int r = 0; r < 2; ++r) {
        const int row = wid * 2 + r;          // local row 0..15
        const int q   = qb + row;
        const float* srow = scores + ((size_t)h * S_ + q) * S_;
        const int*   mrow = mask + (size_t)q * S_;        // mask broadcast over h

        float sv[32];
        #pragma unroll
        for (int j = 0; j < 8; ++j) {
            const int k = j * 256 + lane * 4;
            f32x4 sc = *(const f32x4*)(srow + k);
            i32x4 mk = *(const i32x4*)(mrow + k);
            #pragma unroll
            for (int e = 0; e < 4; ++e)
                sv[j * 4 + e] = (mk[e] != 0) ? NEG_INF_F : sc[e];
        }

        float m = sv[0];
        #pragma unroll
        for (int i = 1; i < 32; ++i) m = fmaxf(m, sv[i]);
        #pragma unroll
        for (int off = 32; off > 0; off >>= 1) m = fmaxf(m, __shfl_xor(m, off, 64));

        float l = 0.f;
        #pragma unroll
        for (int i = 0; i < 32; ++i) { sv[i] = __expf(sv[i] - m); l += sv[i]; }
        #pragma unroll
        for (int off = 32; off > 0; off >>= 1) l += __shfl_xor(l, off, 64);
        const float inv = 1.0f / l;

        float* arow = attn + ((size_t)h * S_ + q) * S_;
        const int swz = (row & 7) << 4;
        #pragma unroll
        for (int j = 0; j < 8; ++j) {
            const int k = j * 256 + lane * 4;
            f32x4 av;
            u16x4 pv;
            #pragma unroll
            for (int e = 0; e < 4; ++e) {
                const float a = sv[j * 4 + e] * inv;
                av[e] = a;
                pv[e] = f2bf(a);
            }
            *(f32x4*)(arow + k) = av;                     // attn out, coalesced 16B
            const int boff = (row * (S_ * 2) + k * 2) ^ swz;
            *(u16x4*)((char*)p_lds + boff) = pv;          // bf16 P, swizzled ds_write_b64
        }
    }
    __syncthreads();

    // ---------- Phase 2: out = P @ v via mfma_f32_16x16x32_bf16, K split x2 ----------
    // Wave w: d-cols [(w&3)*16, +16), K-half (w>>2)*1024.
    const int col  = lane & 15;
    const int kg   = lane >> 4;
    const int d0   = (wid & 3) * 16;
    const int kh   = wid >> 2;
    const int swzA = (col & 7) << 4;
    const float* vcol = v + (size_t)h * S_ * D_ + (d0 + col);

    f32x4 acc = {0.f, 0.f, 0.f, 0.f};
    #pragma unroll 2
    for (int ks2 = 0; ks2 < 32; ++ks2) {
        const int ka = (kh * 32 + ks2) * 32 + kg * 8;     // lane's 8 contiguous k
        const int aoff = (col * (S_ * 2) + ka * 2) ^ swzA;
        s16x8 afrag = *(const s16x8*)((const char*)p_lds + aoff);  // ds_read_b128

        const float* vp = vcol + (size_t)ka * D_;
        s16x8 bfrag;
        #pragma unroll
        for (int i = 0; i < 8; ++i)
            bfrag[i] = (short)f2bf(vp[i * D_]);           // v is L2-resident
        acc = __builtin_amdgcn_mfma_f32_16x16x32_bf16(afrag, bfrag, acc, 0, 0, 0);
    }

    __syncthreads();                       // all p_lds MFMA reads complete
    // Partial-sum reduction through LDS (reuse p_lds as float[2][QT][D_])
    float* red = (float*)p_lds;
    const int rg = (lane >> 4) * 4;        // C/D layout: col=lane&15, row=4*(lane>>4)+j
    #pragma unroll
    for (int j = 0; j < 4; ++j)
        red[kh * (QT * D_) + (rg + j) * D_ + d0 + col] = acc[j];
    __syncthreads();

    // out tile is QT x D_ = 1024 floats; 512 threads x 2
    #pragma unroll
    for (int i = tid; i < QT * D_; i += 512) {
        const int row = i >> 6, c = i & 63;
        outp[((size_t)h * S_ + (qb + row)) * D_ + c] = red[i] + red[QT * D_ + i];
    }
}

extern "C" void kernel_launch(void* const* d_in, const int* in_sizes, int n_in,
                              void* d_out, int out_size, void* d_ws, size_t ws_size,
                              hipStream_t stream) {
    const float* v      = (const float*)d_in[0];  // (1,12,2048,64) f32
    const float* scores = (const float*)d_in[1];  // (1,12,2048,2048) f32
    const int*   mask   = (const int*)d_in[3];    // (1,1,2048,2048) i32
    float* out = (float*)d_out;                   // [out | attn] f32

    dim3 grid(H_ * (S_ / QT));
    dim3 block(512);
    hipLaunchKernelGGL(ra_fused, grid, block, 0, stream, v, scores, mask, out);
}